// Round 14
// baseline (108.964 us; speedup 1.0000x reference)
//
#include <hip/hip_runtime.h>
#include <hip/hip_bf16.h>

typedef __bf16 bf16x8 __attribute__((ext_vector_type(8)));
typedef float f32x4 __attribute__((ext_vector_type(4)));
typedef unsigned short u16x8 __attribute__((ext_vector_type(8)));

#define NB 8
#define NT 2048
#define NC 1024
#define NH 64

__device__ __forceinline__ unsigned short bfbits(float f) {
    return __builtin_bit_cast(unsigned short, (__bf16)f);
}

// ---------------- kernel 1: W -> W^T (bf16) ----------------
// Wt layout: [3][64][1024], order 0=Wq, 1=Wk, 2=Wv
__global__ __launch_bounds__(256) void wt_kernel(const float* __restrict__ Wq,
                                                 const float* __restrict__ Wk,
                                                 const float* __restrict__ Wv,
                                                 unsigned short* __restrict__ Wt) {
    int idx = blockIdx.x * 256 + threadIdx.x;
    int n = idx >> 16;
    int r = idx & 65535;
    int c = r >> 6;
    int h = r & 63;
    const float* W = (n == 0) ? Wq : ((n == 1) ? Wk : Wv);
    float x = W[c * 64 + h];
    Wt[(n << 16) + h * 1024 + c] = bfbits(x);
}

// ---------------- kernel 2: LDS-staged tiled QKV projection (NT loads — keep) ----------------
__global__ __launch_bounds__(256, 4) void proj_kernel(const float* __restrict__ Xv,
                                                      const float* __restrict__ Xk,
                                                      const float* __restrict__ Xq,
                                                      const unsigned short* __restrict__ Wt,
                                                      unsigned short* __restrict__ Q,
                                                      unsigned short* __restrict__ K,
                                                      unsigned short* __restrict__ VT) {
    __shared__ __align__(16) char Xs[64 * 256];   // 64 rows x 128 bf16
    __shared__ __align__(16) char Ws[64 * 256];

    int type = blockIdx.x >> 8;          // 0=Q,1=K,2=V
    int mt   = blockIdx.x & 255;
    int row0 = mt << 6;
    const float* X = (type == 0) ? Xq : ((type == 1) ? Xk : Xv);
    const unsigned short* W = Wt + (type << 16);

    int tid  = threadIdx.x;
    int w    = tid >> 6;
    int lane = tid & 63;
    int lo = lane & 15, hi = lane >> 4;

    f32x4 acc[4];
#pragma unroll
    for (int ct = 0; ct < 4; ++ct) acc[ct] = 0.f;

    for (int kc = 0; kc < 8; ++kc) {
        // ---- issue stage loads (X stream = non-temporal: bypass L3 alloc path) ----
        f32x4 xr[8];
#pragma unroll
        for (int i = 0; i < 8; ++i) {
            int f4 = tid + 256 * i;
            int r  = f4 >> 5, c4 = f4 & 31;
            xr[i] = __builtin_nontemporal_load(
                (const f32x4*)(X + (size_t)(row0 + r) * NC + kc * 128 + c4 * 4));
        }
        u16x8 wr_[4];
#pragma unroll
        for (int i = 0; i < 4; ++i) {
            int s16 = tid + 256 * i;
            int h = s16 >> 4, sl = s16 & 15;
            wr_[i] = *(const u16x8*)(W + h * 1024 + kc * 128 + sl * 8);
        }
        __syncthreads();
#pragma unroll
        for (int i = 0; i < 8; ++i) {
            int f4 = tid + 256 * i;
            int r  = f4 >> 5, c4 = f4 & 31;
            ushort4 bv;
            bv.x = bfbits(xr[i][0]); bv.y = bfbits(xr[i][1]);
            bv.z = bfbits(xr[i][2]); bv.w = bfbits(xr[i][3]);
            int byte = r * 256 + ((c4 * 8) ^ ((r & 7) << 4));
            *(ushort4*)(Xs + byte) = bv;
        }
#pragma unroll
        for (int i = 0; i < 4; ++i) {
            int s16 = tid + 256 * i;
            int h = s16 >> 4, sl = s16 & 15;
            int byte = h * 256 + ((sl * 16) ^ ((h & 7) << 4));
            *(u16x8*)(Ws + byte) = wr_[i];
        }
        __syncthreads();
#pragma unroll
        for (int ks = 0; ks < 4; ++ks) {
            int coff = (ks * 64 + hi * 16) ^ ((lo & 7) << 4);
            bf16x8 af = *(const bf16x8*)(Xs + (w * 16 + lo) * 256 + coff);
#pragma unroll
            for (int ct = 0; ct < 4; ++ct) {
                bf16x8 bf = *(const bf16x8*)(Ws + (ct * 16 + lo) * 256 + coff);
                acc[ct] = __builtin_amdgcn_mfma_f32_16x16x32_bf16(af, bf, acc[ct], 0, 0, 0);
            }
        }
    }

    if (type < 2) {
        unsigned short* O = (type == 0) ? Q : K;
#pragma unroll
        for (int ct = 0; ct < 4; ++ct)
#pragma unroll
            for (int r = 0; r < 4; ++r) {
                int row = row0 + w * 16 + hi * 4 + r;
                int h = lo + 16 * ct;
                O[(size_t)row * NH + h] = bfbits(acc[ct][r]);
            }
    } else {
        int trow = row0 + w * 16 + hi * 4;
        int b = trow >> 11;
        int t = trow & 2047;
#pragma unroll
        for (int ct = 0; ct < 4; ++ct) {
            int h = lo + 16 * ct;
            ushort4 pk;
            pk.x = bfbits(acc[ct][0]);
            pk.y = bfbits(acc[ct][1]);
            pk.z = bfbits(acc[ct][2]);
            pk.w = bfbits(acc[ct][3]);
            *(ushort4*)(VT + (size_t)(b * NH + h) * NT + t) = pk;
        }
    }
}

// ---------------- kernel 3: causal flash attention (R5 straight-line body + prescaled Q) ----------------
__global__ __launch_bounds__(256) void attn_kernel(const unsigned short* __restrict__ Q,
                                                   const unsigned short* __restrict__ K,
                                                   const unsigned short* __restrict__ VT,
                                                   float* __restrict__ out) {
    __shared__ __align__(16) unsigned short p_lds[4 * 512];
    __shared__ __align__(16) float acc_lds[4 * 16 * 64];
    __shared__ float m_lds[4][16];
    __shared__ float l_lds[4][16];

    int b  = blockIdx.x >> 7;
    int qt = blockIdx.x & 127;
    int q0 = qt << 4;
    int w    = threadIdx.x >> 6;
    int lane = threadIdx.x & 63;
    int lo = lane & 15, hi = lane >> 4;

    const float SC = 0.03125f * 1.44269504088896340736f;  // C^-0.5 * log2(e)
    const unsigned short* qb = Q + (size_t)(b * NT + q0 + lo) * NH + hi * 8;
    bf16x8 qr0 = *(const bf16x8*)(qb);
    bf16x8 qr1 = *(const bf16x8*)(qb + 32);
    bf16x8 qf0, qf1;
#pragma unroll
    for (int j = 0; j < 8; ++j) {
        qf0[j] = (__bf16)((float)qr0[j] * SC);
        qf1[j] = (__bf16)((float)qr1[j] * SC);
    }

    int Ctot = (q0 + 16 + 31) >> 5;
    int c0 = (Ctot * w) >> 2;
    int c1 = (Ctot * (w + 1)) >> 2;

    float m[4], l[4];
    f32x4 acc[4];
#pragma unroll
    for (int r = 0; r < 4; ++r) { m[r] = -1e30f; l[r] = 0.f; }
#pragma unroll
    for (int ct = 0; ct < 4; ++ct) acc[ct] = 0.f;

    unsigned short* pl = p_lds + w * 512;

    for (int c = c0; c < c1; ++c) {
        int s0 = c << 5;
        const unsigned short* kb = K + (size_t)(b * NT + s0 + lo) * NH + hi * 8;
        f32x4 S0 = 0.f, S1 = 0.f;
        S0 = __builtin_amdgcn_mfma_f32_16x16x32_bf16(qf0, *(const bf16x8*)(kb), S0, 0, 0, 0);
        S0 = __builtin_amdgcn_mfma_f32_16x16x32_bf16(qf1, *(const bf16x8*)(kb + 32), S0, 0, 0, 0);
        S1 = __builtin_amdgcn_mfma_f32_16x16x32_bf16(qf0, *(const bf16x8*)(kb + 16 * NH), S1, 0, 0, 0);
        S1 = __builtin_amdgcn_mfma_f32_16x16x32_bf16(qf1, *(const bf16x8*)(kb + 16 * NH + 32), S1, 0, 0, 0);

        int s_a = s0 + lo, s_b = s0 + 16 + lo;
        float z0[4], z1[4], mt_[4];
#pragma unroll
        for (int r = 0; r < 4; ++r) {
            int qi = q0 + hi * 4 + r;
            z0[r] = (s_a <= qi) ? S0[r] : -1e30f;
            z1[r] = (s_b <= qi) ? S1[r] : -1e30f;
            mt_[r] = fmaxf(z0[r], z1[r]);
        }
#pragma unroll
        for (int d = 1; d < 16; d <<= 1)
#pragma unroll
            for (int r = 0; r < 4; ++r)
                mt_[r] = fmaxf(mt_[r], __shfl_xor(mt_[r], d, 16));

        float p0[4], p1[4], rs[4];
#pragma unroll
        for (int r = 0; r < 4; ++r) {
            float mn = fmaxf(m[r], mt_[r]);
            float al = exp2f(m[r] - mn);
            int qi = q0 + hi * 4 + r;
            p0[r] = (s_a <= qi) ? exp2f(z0[r] - mn) : 0.f;
            p1[r] = (s_b <= qi) ? exp2f(z1[r] - mn) : 0.f;
            rs[r] = p0[r] + p1[r];
            m[r] = mn;
            l[r] *= al;
            acc[0][r] *= al; acc[1][r] *= al; acc[2][r] *= al; acc[3][r] *= al;
        }
#pragma unroll
        for (int d = 1; d < 16; d <<= 1)
#pragma unroll
            for (int r = 0; r < 4; ++r)
                rs[r] += __shfl_xor(rs[r], d, 16);
#pragma unroll
        for (int r = 0; r < 4; ++r) {
            l[r] += rs[r];
            int ql = hi * 4 + r;
            pl[ql * 32 + lo]      = bfbits(p0[r]);
            pl[ql * 32 + 16 + lo] = bfbits(p1[r]);
        }
        bf16x8 pa = *(const bf16x8*)(pl + lo * 32 + hi * 8);
        const unsigned short* vb = VT + (size_t)(b * NH + lo) * NT + s0 + hi * 8;
#pragma unroll
        for (int ct = 0; ct < 4; ++ct) {
            bf16x8 vv = *(const bf16x8*)(vb + ct * 16 * NT);
            acc[ct] = __builtin_amdgcn_mfma_f32_16x16x32_bf16(pa, vv, acc[ct], 0, 0, 0);
        }
    }

    // dump per-wave partial state
#pragma unroll
    for (int r = 0; r < 4; ++r) {
        int ql = hi * 4 + r;
#pragma unroll
        for (int ct = 0; ct < 4; ++ct)
            acc_lds[(w * 16 + ql) * 64 + lo + 16 * ct] = acc[ct][r];
    }
    if (lo == 0) {
#pragma unroll
        for (int r = 0; r < 4; ++r) {
            m_lds[w][hi * 4 + r] = m[r];
            l_lds[w][hi * 4 + r] = l[r];
        }
    }
    __syncthreads();

    // merge 4 s-splits
    int q  = threadIdx.x >> 4;
    int h0 = (threadIdx.x & 15) << 2;
    float M = fmaxf(fmaxf(m_lds[0][q], m_lds[1][q]), fmaxf(m_lds[2][q], m_lds[3][q]));
    float L = 0.f;
    float ox = 0.f, oy = 0.f, oz = 0.f, ow = 0.f;
#pragma unroll
    for (int ww = 0; ww < 4; ++ww) {
        float a_ = exp2f(m_lds[ww][q] - M);
        L += a_ * l_lds[ww][q];
        const float* p = acc_lds + (ww * 16 + q) * 64 + h0;
        ox += a_ * p[0]; oy += a_ * p[1]; oz += a_ * p[2]; ow += a_ * p[3];
    }
    float inv = 1.0f / L;
    float4 res = make_float4(ox * inv, oy * inv, oz * inv, ow * inv);
    *(float4*)(out + (size_t)(b * NT + q0 + q) * NH + h0) = res;
}

extern "C" void kernel_launch(void* const* d_in, const int* in_sizes, int n_in,
                              void* d_out, int out_size, void* d_ws, size_t ws_size,
                              hipStream_t stream) {
    const float* values  = (const float*)d_in[0];
    const float* keys    = (const float*)d_in[1];
    const float* queries = (const float*)d_in[2];
    const float* Wk = (const float*)d_in[3];
    const float* Wq = (const float*)d_in[4];
    const float* Wv = (const float*)d_in[5];
    float* out = (float*)d_out;

    unsigned short* Wt = (unsigned short*)d_ws;        // 196608 ushorts
    unsigned short* Qb = Wt + 196608;                  // Q,K,VT: 3x1048576 ushorts
    unsigned short* Kb = Qb + 1048576;
    unsigned short* VT = Kb + 1048576;

    wt_kernel<<<768, 256, 0, stream>>>(Wq, Wk, Wv, Wt);
    proj_kernel<<<768, 256, 0, stream>>>(values, keys, queries, Wt, Qb, Kb, VT);
    attn_kernel<<<1024, 256, 0, stream>>>(Qb, Kb, VT, out);
}

// Round 15
// 88.663 us; speedup vs baseline: 1.2290x; 1.2290x over previous
//
#include <hip/hip_runtime.h>
#include <hip/hip_bf16.h>

typedef __bf16 bf16x8 __attribute__((ext_vector_type(8)));
typedef float f32x4 __attribute__((ext_vector_type(4)));
typedef unsigned short u16x8 __attribute__((ext_vector_type(8)));

#define NB 8
#define NT 2048
#define NC 1024
#define NH 64

__device__ __forceinline__ unsigned short bfbits(float f) {
    return __builtin_bit_cast(unsigned short, (__bf16)f);
}

// ---------------- kernel 1: W -> W^T (bf16) ----------------
// Wt layout: [3][64][1024], order 0=Wq, 1=Wk, 2=Wv
__global__ __launch_bounds__(256) void wt_kernel(const float* __restrict__ Wq,
                                                 const float* __restrict__ Wk,
                                                 const float* __restrict__ Wv,
                                                 unsigned short* __restrict__ Wt) {
    int idx = blockIdx.x * 256 + threadIdx.x;
    int n = idx >> 16;
    int r = idx & 65535;
    int c = r >> 6;
    int h = r & 63;
    const float* W = (n == 0) ? Wq : ((n == 1) ? Wk : Wv);
    float x = W[c * 64 + h];
    Wt[(n << 16) + h * 1024 + c] = bfbits(x);
}

// ---------------- kernel 2: LDS-staged tiled QKV projection (NT loads — keep) ----------------
__global__ __launch_bounds__(256, 4) void proj_kernel(const float* __restrict__ Xv,
                                                      const float* __restrict__ Xk,
                                                      const float* __restrict__ Xq,
                                                      const unsigned short* __restrict__ Wt,
                                                      unsigned short* __restrict__ Q,
                                                      unsigned short* __restrict__ K,
                                                      unsigned short* __restrict__ VT) {
    __shared__ __align__(16) char Xs[64 * 256];   // 64 rows x 128 bf16
    __shared__ __align__(16) char Ws[64 * 256];

    int type = blockIdx.x >> 8;          // 0=Q,1=K,2=V
    int mt   = blockIdx.x & 255;
    int row0 = mt << 6;
    const float* X = (type == 0) ? Xq : ((type == 1) ? Xk : Xv);
    const unsigned short* W = Wt + (type << 16);

    int tid  = threadIdx.x;
    int w    = tid >> 6;
    int lane = tid & 63;
    int lo = lane & 15, hi = lane >> 4;

    f32x4 acc[4];
#pragma unroll
    for (int ct = 0; ct < 4; ++ct) acc[ct] = 0.f;

    for (int kc = 0; kc < 8; ++kc) {
        // ---- issue stage loads (X stream = non-temporal: bypass L3 alloc path) ----
        f32x4 xr[8];
#pragma unroll
        for (int i = 0; i < 8; ++i) {
            int f4 = tid + 256 * i;
            int r  = f4 >> 5, c4 = f4 & 31;
            xr[i] = __builtin_nontemporal_load(
                (const f32x4*)(X + (size_t)(row0 + r) * NC + kc * 128 + c4 * 4));
        }
        u16x8 wr_[4];
#pragma unroll
        for (int i = 0; i < 4; ++i) {
            int s16 = tid + 256 * i;
            int h = s16 >> 4, sl = s16 & 15;
            wr_[i] = *(const u16x8*)(W + h * 1024 + kc * 128 + sl * 8);
        }
        __syncthreads();
#pragma unroll
        for (int i = 0; i < 8; ++i) {
            int f4 = tid + 256 * i;
            int r  = f4 >> 5, c4 = f4 & 31;
            ushort4 bv;
            bv.x = bfbits(xr[i][0]); bv.y = bfbits(xr[i][1]);
            bv.z = bfbits(xr[i][2]); bv.w = bfbits(xr[i][3]);
            int byte = r * 256 + ((c4 * 8) ^ ((r & 7) << 4));
            *(ushort4*)(Xs + byte) = bv;
        }
#pragma unroll
        for (int i = 0; i < 4; ++i) {
            int s16 = tid + 256 * i;
            int h = s16 >> 4, sl = s16 & 15;
            int byte = h * 256 + ((sl * 16) ^ ((h & 7) << 4));
            *(u16x8*)(Ws + byte) = wr_[i];
        }
        __syncthreads();
#pragma unroll
        for (int ks = 0; ks < 4; ++ks) {
            int coff = (ks * 64 + hi * 16) ^ ((lo & 7) << 4);
            bf16x8 af = *(const bf16x8*)(Xs + (w * 16 + lo) * 256 + coff);
#pragma unroll
            for (int ct = 0; ct < 4; ++ct) {
                bf16x8 bf = *(const bf16x8*)(Ws + (ct * 16 + lo) * 256 + coff);
                acc[ct] = __builtin_amdgcn_mfma_f32_16x16x32_bf16(af, bf, acc[ct], 0, 0, 0);
            }
        }
    }

    if (type < 2) {
        unsigned short* O = (type == 0) ? Q : K;
#pragma unroll
        for (int ct = 0; ct < 4; ++ct)
#pragma unroll
            for (int r = 0; r < 4; ++r) {
                int row = row0 + w * 16 + hi * 4 + r;
                int h = lo + 16 * ct;
                O[(size_t)row * NH + h] = bfbits(acc[ct][r]);
            }
    } else {
        int trow = row0 + w * 16 + hi * 4;
        int b = trow >> 11;
        int t = trow & 2047;
#pragma unroll
        for (int ct = 0; ct < 4; ++ct) {
            int h = lo + 16 * ct;
            ushort4 pk;
            pk.x = bfbits(acc[ct][0]);
            pk.y = bfbits(acc[ct][1]);
            pk.z = bfbits(acc[ct][2]);
            pk.w = bfbits(acc[ct][3]);
            *(ushort4*)(VT + (size_t)(b * NH + h) * NT + t) = pk;
        }
    }
}

// ---------------- kernel 3: causal flash attention (XCD-pinned batches) ----------------
// b = blockIdx & 7: round-robin dispatch pins all q-tiles of batch b to XCD b,
// making K/V/Q/VT for b resident in that XCD's 4MB L2 (~1.25MB working set).
__global__ __launch_bounds__(256) void attn_kernel(const unsigned short* __restrict__ Q,
                                                   const unsigned short* __restrict__ K,
                                                   const unsigned short* __restrict__ VT,
                                                   float* __restrict__ out) {
    __shared__ __align__(16) unsigned short p_lds[4 * 512];
    __shared__ __align__(16) float acc_lds[4 * 16 * 64];
    __shared__ float m_lds[4][16];
    __shared__ float l_lds[4][16];

    int b  = blockIdx.x & 7;          // XCD-pinned batch
    int qt = blockIdx.x >> 3;
    int q0 = qt << 4;
    int w    = threadIdx.x >> 6;
    int lane = threadIdx.x & 63;
    int lo = lane & 15, hi = lane >> 4;

    const float SC = 0.03125f * 1.44269504088896340736f;  // C^-0.5 * log2(e)
    const unsigned short* qb = Q + (size_t)(b * NT + q0 + lo) * NH + hi * 8;
    bf16x8 qr0 = *(const bf16x8*)(qb);
    bf16x8 qr1 = *(const bf16x8*)(qb + 32);
    bf16x8 qf0, qf1;
#pragma unroll
    for (int j = 0; j < 8; ++j) {
        qf0[j] = (__bf16)((float)qr0[j] * SC);
        qf1[j] = (__bf16)((float)qr1[j] * SC);
    }

    int Ctot = (q0 + 16 + 31) >> 5;
    int c0 = (Ctot * w) >> 2;
    int c1 = (Ctot * (w + 1)) >> 2;

    float m[4], l[4];
    f32x4 acc[4];
#pragma unroll
    for (int r = 0; r < 4; ++r) { m[r] = -1e30f; l[r] = 0.f; }
#pragma unroll
    for (int ct = 0; ct < 4; ++ct) acc[ct] = 0.f;

    unsigned short* pl = p_lds + w * 512;

    for (int c = c0; c < c1; ++c) {
        int s0 = c << 5;
        const unsigned short* kb = K + (size_t)(b * NT + s0 + lo) * NH + hi * 8;
        f32x4 S0 = 0.f, S1 = 0.f;
        S0 = __builtin_amdgcn_mfma_f32_16x16x32_bf16(qf0, *(const bf16x8*)(kb), S0, 0, 0, 0);
        S0 = __builtin_amdgcn_mfma_f32_16x16x32_bf16(qf1, *(const bf16x8*)(kb + 32), S0, 0, 0, 0);
        S1 = __builtin_amdgcn_mfma_f32_16x16x32_bf16(qf0, *(const bf16x8*)(kb + 16 * NH), S1, 0, 0, 0);
        S1 = __builtin_amdgcn_mfma_f32_16x16x32_bf16(qf1, *(const bf16x8*)(kb + 16 * NH + 32), S1, 0, 0, 0);

        int s_a = s0 + lo, s_b = s0 + 16 + lo;
        float z0[4], z1[4], mt_[4];
#pragma unroll
        for (int r = 0; r < 4; ++r) {
            int qi = q0 + hi * 4 + r;
            z0[r] = (s_a <= qi) ? S0[r] : -1e30f;
            z1[r] = (s_b <= qi) ? S1[r] : -1e30f;
            mt_[r] = fmaxf(z0[r], z1[r]);
        }
#pragma unroll
        for (int d = 1; d < 16; d <<= 1)
#pragma unroll
            for (int r = 0; r < 4; ++r)
                mt_[r] = fmaxf(mt_[r], __shfl_xor(mt_[r], d, 16));

        float p0[4], p1[4], rs[4];
#pragma unroll
        for (int r = 0; r < 4; ++r) {
            float mn = fmaxf(m[r], mt_[r]);
            float al = exp2f(m[r] - mn);
            int qi = q0 + hi * 4 + r;
            p0[r] = (s_a <= qi) ? exp2f(z0[r] - mn) : 0.f;
            p1[r] = (s_b <= qi) ? exp2f(z1[r] - mn) : 0.f;
            rs[r] = p0[r] + p1[r];
            m[r] = mn;
            l[r] *= al;
            acc[0][r] *= al; acc[1][r] *= al; acc[2][r] *= al; acc[3][r] *= al;
        }
#pragma unroll
        for (int d = 1; d < 16; d <<= 1)
#pragma unroll
            for (int r = 0; r < 4; ++r)
                rs[r] += __shfl_xor(rs[r], d, 16);
#pragma unroll
        for (int r = 0; r < 4; ++r) {
            l[r] += rs[r];
            int ql = hi * 4 + r;
            pl[ql * 32 + lo]      = bfbits(p0[r]);
            pl[ql * 32 + 16 + lo] = bfbits(p1[r]);
        }
        bf16x8 pa = *(const bf16x8*)(pl + lo * 32 + hi * 8);
        const unsigned short* vb = VT + (size_t)(b * NH + lo) * NT + s0 + hi * 8;
#pragma unroll
        for (int ct = 0; ct < 4; ++ct) {
            bf16x8 vv = *(const bf16x8*)(vb + ct * 16 * NT);
            acc[ct] = __builtin_amdgcn_mfma_f32_16x16x32_bf16(pa, vv, acc[ct], 0, 0, 0);
        }
    }

    // dump per-wave partial state
#pragma unroll
    for (int r = 0; r < 4; ++r) {
        int ql = hi * 4 + r;
#pragma unroll
        for (int ct = 0; ct < 4; ++ct)
            acc_lds[(w * 16 + ql) * 64 + lo + 16 * ct] = acc[ct][r];
    }
    if (lo == 0) {
#pragma unroll
        for (int r = 0; r < 4; ++r) {
            m_lds[w][hi * 4 + r] = m[r];
            l_lds[w][hi * 4 + r] = l[r];
        }
    }
    __syncthreads();

    // merge 4 s-splits
    int q  = threadIdx.x >> 4;
    int h0 = (threadIdx.x & 15) << 2;
    float M = fmaxf(fmaxf(m_lds[0][q], m_lds[1][q]), fmaxf(m_lds[2][q], m_lds[3][q]));
    float L = 0.f;
    float ox = 0.f, oy = 0.f, oz = 0.f, ow = 0.f;
#pragma unroll
    for (int ww = 0; ww < 4; ++ww) {
        float a_ = exp2f(m_lds[ww][q] - M);
        L += a_ * l_lds[ww][q];
        const float* p = acc_lds + (ww * 16 + q) * 64 + h0;
        ox += a_ * p[0]; oy += a_ * p[1]; oz += a_ * p[2]; ow += a_ * p[3];
    }
    float inv = 1.0f / L;
    float4 res = make_float4(ox * inv, oy * inv, oz * inv, ow * inv);
    *(float4*)(out + (size_t)(b * NT + q0 + q) * NH + h0) = res;
}

extern "C" void kernel_launch(void* const* d_in, const int* in_sizes, int n_in,
                              void* d_out, int out_size, void* d_ws, size_t ws_size,
                              hipStream_t stream) {
    const float* values  = (const float*)d_in[0];
    const float* keys    = (const float*)d_in[1];
    const float* queries = (const float*)d_in[2];
    const float* Wk = (const float*)d_in[3];
    const float* Wq = (const float*)d_in[4];
    const float* Wv = (const float*)d_in[5];
    float* out = (float*)d_out;

    unsigned short* Wt = (unsigned short*)d_ws;        // 196608 ushorts
    unsigned short* Qb = Wt + 196608;                  // Q,K,VT: 3x1048576 ushorts
    unsigned short* Kb = Qb + 1048576;
    unsigned short* VT = Kb + 1048576;

    wt_kernel<<<768, 256, 0, stream>>>(Wq, Wk, Wv, Wt);
    proj_kernel<<<768, 256, 0, stream>>>(values, keys, queries, Wt, Qb, Kb, VT);
    attn_kernel<<<1024, 256, 0, stream>>>(Qb, Kb, VT, out);
}

// Round 16
// 82.594 us; speedup vs baseline: 1.3193x; 1.0735x over previous
//
#include <hip/hip_runtime.h>
#include <hip/hip_bf16.h>

typedef __bf16 bf16x8 __attribute__((ext_vector_type(8)));
typedef float f32x4 __attribute__((ext_vector_type(4)));
typedef unsigned short u16x8 __attribute__((ext_vector_type(8)));

#define NB 8
#define NT 2048
#define NC 1024
#define NH 64

__device__ __forceinline__ unsigned short bfbits(float f) {
    return __builtin_bit_cast(unsigned short, (__bf16)f);
}

// ---------------- kernel 1: W -> W^T (bf16) ----------------
__global__ __launch_bounds__(256) void wt_kernel(const float* __restrict__ Wq,
                                                 const float* __restrict__ Wk,
                                                 const float* __restrict__ Wv,
                                                 unsigned short* __restrict__ Wt) {
    int idx = blockIdx.x * 256 + threadIdx.x;
    int n = idx >> 16;
    int r = idx & 65535;
    int c = r >> 6;
    int h = r & 63;
    const float* W = (n == 0) ? Wq : ((n == 1) ? Wk : Wv);
    float x = W[c * 64 + h];
    Wt[(n << 16) + h * 1024 + c] = bfbits(x);
}

// ---------------- kernel 2: LDS-staged tiled QKV projection (NT loads — keep) ----------------
__global__ __launch_bounds__(256, 4) void proj_kernel(const float* __restrict__ Xv,
                                                      const float* __restrict__ Xk,
                                                      const float* __restrict__ Xq,
                                                      const unsigned short* __restrict__ Wt,
                                                      unsigned short* __restrict__ Q,
                                                      unsigned short* __restrict__ K,
                                                      unsigned short* __restrict__ VT) {
    __shared__ __align__(16) char Xs[64 * 256];   // 64 rows x 128 bf16
    __shared__ __align__(16) char Ws[64 * 256];

    int type = blockIdx.x >> 8;          // 0=Q,1=K,2=V
    int mt   = blockIdx.x & 255;
    int row0 = mt << 6;
    const float* X = (type == 0) ? Xq : ((type == 1) ? Xk : Xv);
    const unsigned short* W = Wt + (type << 16);

    int tid  = threadIdx.x;
    int w    = tid >> 6;
    int lane = tid & 63;
    int lo = lane & 15, hi = lane >> 4;

    f32x4 acc[4];
#pragma unroll
    for (int ct = 0; ct < 4; ++ct) acc[ct] = 0.f;

    for (int kc = 0; kc < 8; ++kc) {
        f32x4 xr[8];
#pragma unroll
        for (int i = 0; i < 8; ++i) {
            int f4 = tid + 256 * i;
            int r  = f4 >> 5, c4 = f4 & 31;
            xr[i] = __builtin_nontemporal_load(
                (const f32x4*)(X + (size_t)(row0 + r) * NC + kc * 128 + c4 * 4));
        }
        u16x8 wr_[4];
#pragma unroll
        for (int i = 0; i < 4; ++i) {
            int s16 = tid + 256 * i;
            int h = s16 >> 4, sl = s16 & 15;
            wr_[i] = *(const u16x8*)(W + h * 1024 + kc * 128 + sl * 8);
        }
        __syncthreads();
#pragma unroll
        for (int i = 0; i < 8; ++i) {
            int f4 = tid + 256 * i;
            int r  = f4 >> 5, c4 = f4 & 31;
            ushort4 bv;
            bv.x = bfbits(xr[i][0]); bv.y = bfbits(xr[i][1]);
            bv.z = bfbits(xr[i][2]); bv.w = bfbits(xr[i][3]);
            int byte = r * 256 + ((c4 * 8) ^ ((r & 7) << 4));
            *(ushort4*)(Xs + byte) = bv;
        }
#pragma unroll
        for (int i = 0; i < 4; ++i) {
            int s16 = tid + 256 * i;
            int h = s16 >> 4, sl = s16 & 15;
            int byte = h * 256 + ((sl * 16) ^ ((h & 7) << 4));
            *(u16x8*)(Ws + byte) = wr_[i];
        }
        __syncthreads();
#pragma unroll
        for (int ks = 0; ks < 4; ++ks) {
            int coff = (ks * 64 + hi * 16) ^ ((lo & 7) << 4);
            bf16x8 af = *(const bf16x8*)(Xs + (w * 16 + lo) * 256 + coff);
#pragma unroll
            for (int ct = 0; ct < 4; ++ct) {
                bf16x8 bf = *(const bf16x8*)(Ws + (ct * 16 + lo) * 256 + coff);
                acc[ct] = __builtin_amdgcn_mfma_f32_16x16x32_bf16(af, bf, acc[ct], 0, 0, 0);
            }
        }
    }

    if (type < 2) {
        unsigned short* O = (type == 0) ? Q : K;
#pragma unroll
        for (int ct = 0; ct < 4; ++ct)
#pragma unroll
            for (int r = 0; r < 4; ++r) {
                int row = row0 + w * 16 + hi * 4 + r;
                int h = lo + 16 * ct;
                O[(size_t)row * NH + h] = bfbits(acc[ct][r]);
            }
    } else {
        int trow = row0 + w * 16 + hi * 4;
        int b = trow >> 11;
        int t = trow & 2047;
#pragma unroll
        for (int ct = 0; ct < 4; ++ct) {
            int h = lo + 16 * ct;
            ushort4 pk;
            pk.x = bfbits(acc[ct][0]);
            pk.y = bfbits(acc[ct][1]);
            pk.z = bfbits(acc[ct][2]);
            pk.w = bfbits(acc[ct][3]);
            *(ushort4*)(VT + (size_t)(b * NH + h) * NT + t) = pk;
        }
    }
}

// ---------------- kernel 3: causal flash attention ----------------
// XCD-pinned (b = blockIdx&7) + complementary-pair balancing: block j handles
// q-tiles j and 127-j (constant total work) + K[c+1]/V[c] register pipeline.
__global__ __launch_bounds__(256) void attn_kernel(const unsigned short* __restrict__ Q,
                                                   const unsigned short* __restrict__ K,
                                                   const unsigned short* __restrict__ VT,
                                                   float* __restrict__ out) {
    __shared__ __align__(16) unsigned short p_lds[4 * 512];
    __shared__ __align__(16) float acc_lds[4 * 16 * 64];
    __shared__ float m_lds[4][16];
    __shared__ float l_lds[4][16];

    int b = blockIdx.x & 7;           // XCD-pinned batch
    int j = blockIdx.x >> 3;          // 0..63 pair index
    int w    = threadIdx.x >> 6;
    int lane = threadIdx.x & 63;
    int lo = lane & 15, hi = lane >> 4;

    const float SC = 0.03125f * 1.44269504088896340736f;  // C^-0.5 * log2(e)
    unsigned short* pl = p_lds + w * 512;

    for (int t2 = 0; t2 < 2; ++t2) {
        int qt = t2 ? (127 - j) : j;
        int q0 = qt << 4;

        const unsigned short* qb = Q + (size_t)(b * NT + q0 + lo) * NH + hi * 8;
        bf16x8 qr0 = *(const bf16x8*)(qb);
        bf16x8 qr1 = *(const bf16x8*)(qb + 32);
        bf16x8 qf0, qf1;
#pragma unroll
        for (int jj = 0; jj < 8; ++jj) {
            qf0[jj] = (__bf16)((float)qr0[jj] * SC);
            qf1[jj] = (__bf16)((float)qr1[jj] * SC);
        }

        int Ctot = (q0 + 47) >> 5;
        int c0 = (Ctot * w) >> 2;
        int c1 = (Ctot * (w + 1)) >> 2;

        float m[4], l[4];
        f32x4 acc[4];
#pragma unroll
        for (int r = 0; r < 4; ++r) { m[r] = -1e30f; l[r] = 0.f; }
#pragma unroll
        for (int ct = 0; ct < 4; ++ct) acc[ct] = 0.f;

        // K prologue for chunk c0
        const unsigned short* kp = K + (size_t)(b * NT + (c0 << 5) + lo) * NH + hi * 8;
        bf16x8 kn0 = *(const bf16x8*)(kp);
        bf16x8 kn1 = *(const bf16x8*)(kp + 32);
        bf16x8 kn2 = *(const bf16x8*)(kp + 16 * NH);
        bf16x8 kn3 = *(const bf16x8*)(kp + 16 * NH + 32);

        for (int c = c0; c < c1; ++c) {
            int s0 = c << 5;
            bf16x8 k0 = kn0, k1 = kn1, k2 = kn2, k3 = kn3;
            // prefetch K for chunk c+1 (latency hidden under this chunk)
            if (c + 1 < c1) {
                const unsigned short* kp2 = K + (size_t)(b * NT + ((c + 1) << 5) + lo) * NH + hi * 8;
                kn0 = *(const bf16x8*)(kp2);
                kn1 = *(const bf16x8*)(kp2 + 32);
                kn2 = *(const bf16x8*)(kp2 + 16 * NH);
                kn3 = *(const bf16x8*)(kp2 + 16 * NH + 32);
            }
            f32x4 S0 = 0.f, S1 = 0.f;
            S0 = __builtin_amdgcn_mfma_f32_16x16x32_bf16(qf0, k0, S0, 0, 0, 0);
            S0 = __builtin_amdgcn_mfma_f32_16x16x32_bf16(qf1, k1, S0, 0, 0, 0);
            S1 = __builtin_amdgcn_mfma_f32_16x16x32_bf16(qf0, k2, S1, 0, 0, 0);
            S1 = __builtin_amdgcn_mfma_f32_16x16x32_bf16(qf1, k3, S1, 0, 0, 0);

            // V loads issued before softmax: L2 latency hides under VALU work
            const unsigned short* vb = VT + (size_t)(b * NH + lo) * NT + s0 + hi * 8;
            bf16x8 vv0 = *(const bf16x8*)(vb);
            bf16x8 vv1 = *(const bf16x8*)(vb + 16 * NT);
            bf16x8 vv2 = *(const bf16x8*)(vb + 32 * NT);
            bf16x8 vv3 = *(const bf16x8*)(vb + 48 * NT);

            int s_a = s0 + lo, s_b = s0 + 16 + lo;
            float z0[4], z1[4], mt_[4];
#pragma unroll
            for (int r = 0; r < 4; ++r) {
                int qi = q0 + hi * 4 + r;
                z0[r] = (s_a <= qi) ? S0[r] : -1e30f;
                z1[r] = (s_b <= qi) ? S1[r] : -1e30f;
                mt_[r] = fmaxf(z0[r], z1[r]);
            }
#pragma unroll
            for (int d = 1; d < 16; d <<= 1)
#pragma unroll
                for (int r = 0; r < 4; ++r)
                    mt_[r] = fmaxf(mt_[r], __shfl_xor(mt_[r], d, 16));

            float p0[4], p1[4], rs[4];
#pragma unroll
            for (int r = 0; r < 4; ++r) {
                float mn = fmaxf(m[r], mt_[r]);
                float al = exp2f(m[r] - mn);
                int qi = q0 + hi * 4 + r;
                p0[r] = (s_a <= qi) ? exp2f(z0[r] - mn) : 0.f;
                p1[r] = (s_b <= qi) ? exp2f(z1[r] - mn) : 0.f;
                rs[r] = p0[r] + p1[r];
                m[r] = mn;
                l[r] *= al;
                acc[0][r] *= al; acc[1][r] *= al; acc[2][r] *= al; acc[3][r] *= al;
            }
#pragma unroll
            for (int d = 1; d < 16; d <<= 1)
#pragma unroll
                for (int r = 0; r < 4; ++r)
                    rs[r] += __shfl_xor(rs[r], d, 16);
#pragma unroll
            for (int r = 0; r < 4; ++r) {
                l[r] += rs[r];
                int ql = hi * 4 + r;
                pl[ql * 32 + lo]      = bfbits(p0[r]);
                pl[ql * 32 + 16 + lo] = bfbits(p1[r]);
            }
            bf16x8 pa = *(const bf16x8*)(pl + lo * 32 + hi * 8);
            acc[0] = __builtin_amdgcn_mfma_f32_16x16x32_bf16(pa, vv0, acc[0], 0, 0, 0);
            acc[1] = __builtin_amdgcn_mfma_f32_16x16x32_bf16(pa, vv1, acc[1], 0, 0, 0);
            acc[2] = __builtin_amdgcn_mfma_f32_16x16x32_bf16(pa, vv2, acc[2], 0, 0, 0);
            acc[3] = __builtin_amdgcn_mfma_f32_16x16x32_bf16(pa, vv3, acc[3], 0, 0, 0);
        }

        // dump per-wave partial state
#pragma unroll
        for (int r = 0; r < 4; ++r) {
            int ql = hi * 4 + r;
#pragma unroll
            for (int ct = 0; ct < 4; ++ct)
                acc_lds[(w * 16 + ql) * 64 + lo + 16 * ct] = acc[ct][r];
        }
        if (lo == 0) {
#pragma unroll
            for (int r = 0; r < 4; ++r) {
                m_lds[w][hi * 4 + r] = m[r];
                l_lds[w][hi * 4 + r] = l[r];
            }
        }
        __syncthreads();

        // merge 4 s-splits
        int q  = threadIdx.x >> 4;
        int h0 = (threadIdx.x & 15) << 2;
        float M = fmaxf(fmaxf(m_lds[0][q], m_lds[1][q]), fmaxf(m_lds[2][q], m_lds[3][q]));
        float L = 0.f;
        float ox = 0.f, oy = 0.f, oz = 0.f, ow = 0.f;
#pragma unroll
        for (int ww = 0; ww < 4; ++ww) {
            float a_ = exp2f(m_lds[ww][q] - M);
            L += a_ * l_lds[ww][q];
            const float* p = acc_lds + (ww * 16 + q) * 64 + h0;
            ox += a_ * p[0]; oy += a_ * p[1]; oz += a_ * p[2]; ow += a_ * p[3];
        }
        float inv = 1.0f / L;
        float4 res = make_float4(ox * inv, oy * inv, oz * inv, ow * inv);
        *(float4*)(out + (size_t)(b * NT + q0 + q) * NH + h0) = res;
        __syncthreads();   // LDS reused by next tile
    }
}

extern "C" void kernel_launch(void* const* d_in, const int* in_sizes, int n_in,
                              void* d_out, int out_size, void* d_ws, size_t ws_size,
                              hipStream_t stream) {
    const float* values  = (const float*)d_in[0];
    const float* keys    = (const float*)d_in[1];
    const float* queries = (const float*)d_in[2];
    const float* Wk = (const float*)d_in[3];
    const float* Wq = (const float*)d_in[4];
    const float* Wv = (const float*)d_in[5];
    float* out = (float*)d_out;

    unsigned short* Wt = (unsigned short*)d_ws;        // 196608 ushorts
    unsigned short* Qb = Wt + 196608;                  // Q,K,VT: 3x1048576 ushorts
    unsigned short* Kb = Qb + 1048576;
    unsigned short* VT = Kb + 1048576;

    wt_kernel<<<768, 256, 0, stream>>>(Wq, Wk, Wv, Wt);
    proj_kernel<<<768, 256, 0, stream>>>(values, keys, queries, Wt, Qb, Kb, VT);
    attn_kernel<<<512, 256, 0, stream>>>(Qb, Kb, VT, out);
}